// Round 9
// baseline (681.629 us; speedup 1.0000x reference)
//
#include <hip/hip_runtime.h>

typedef __attribute__((ext_vector_type(8))) short short8;
typedef __attribute__((ext_vector_type(4))) float f32x4;
typedef __attribute__((ext_vector_type(4))) _Float16 half4;
typedef __attribute__((ext_vector_type(8))) _Float16 half8;
typedef __attribute__((ext_vector_type(2))) __fp16 fp16x2;

#define NSEQ 2048
#define DIM  768
#define NH   8
#define DH   96

__device__ __forceinline__ unsigned short f2bf(float f) {
  unsigned int u = __float_as_uint(f);
  u += 0x7fffu + ((u >> 16) & 1u);   // RNE
  return (unsigned short)(u >> 16);
}

__device__ __forceinline__ float fexp2(float x) {
#if __has_builtin(__builtin_amdgcn_exp2f)
  return __builtin_amdgcn_exp2f(x);
#else
  return exp2f(x);
#endif
}

__device__ __forceinline__ void glds16(const void* g, void* l) {
  __builtin_amdgcn_global_load_lds((const __attribute__((address_space(1))) void*)g,
                                   (__attribute__((address_space(3))) void*)l, 16, 0, 0);
}

// ---- device-scope grid barrier (all blocks co-resident by construction) ----
// release: per-thread threadfence; arrival: one AGENT atomic per block; acquire:
// atomic-acquire load + threadfence. Bounded spin avoids an infinite hang if the
// residency assumption is ever violated (would then fail absmax visibly).
__device__ __forceinline__ void gridbar(unsigned int* sync, unsigned int target) {
  __threadfence();
  __syncthreads();
  if (threadIdx.x == 0) {
    __hip_atomic_fetch_add(sync, 1u, __ATOMIC_RELEASE, __HIP_MEMORY_SCOPE_AGENT);
    unsigned int cap = 0;
    while (__hip_atomic_load(sync, __ATOMIC_ACQUIRE, __HIP_MEMORY_SCOPE_AGENT) < target
           && cap < (4u << 20)) { __builtin_amdgcn_s_sleep(8); ++cap; }
  }
  __syncthreads();
  __threadfence();
}

// =============================== phase bodies (r2-exact) ===============================

__device__ __forceinline__ void prep_cvt_job(int j, const float* __restrict__ x,
                                             unsigned short* __restrict__ xb) {
  int i = j * 256 + threadIdx.x;
  float4 v = ((const float4*)x)[i];
  ushort4 o;
  o.x = f2bf(v.x); o.y = f2bf(v.y); o.z = f2bf(v.z); o.w = f2bf(v.w);
  ((ushort4*)xb)[i] = o;
}

__device__ __forceinline__ void prep_wt_job(int r, const float* __restrict__ Wqkv,
                                            unsigned short* __restrict__ wqkvT,
                                            const float* __restrict__ Wo,
                                            unsigned short* __restrict__ woT,
                                            unsigned char* smem) {
  float* tile = (float*)smem;                    // [32][33]
  const float* W; unsigned short* WT; int ncols, bx, by;
  if (r < 1728) { W = Wqkv; WT = wqkvT; ncols = 2304; bx = r % 72; by = r / 72; }
  else          { int q = r - 1728; W = Wo; WT = woT; ncols = 768; bx = q % 24; by = q / 24; }
  int tx = threadIdx.x & 31, ty = threadIdx.x >> 5;   // 32 x 8
  int c0 = bx * 32, r0 = by * 32;
#pragma unroll
  for (int i = 0; i < 4; i++)
    tile[(ty + i * 8) * 33 + tx] = W[(size_t)(r0 + ty + i * 8) * ncols + c0 + tx];
  __syncthreads();
#pragma unroll
  for (int i = 0; i < 4; i++)
    WT[(size_t)(c0 + ty + i * 8) * 768 + r0 + tx] = f2bf(tile[tx * 33 + ty + i * 8]);
  __syncthreads();                               // tile reusable for next job
}

// bf16 GEMM tile, A[M][768] @ Bt[N][768]^T, 128x128, BK=64 (r2-exact body).
// EPI 0: scatter -> Q (scaled), K (bf16), V^T (fp16). EPI 1: +bias, fp32 out.
template <int EPI>
__device__ __forceinline__ void gemm_tile(
    int bx, int by,
    const unsigned short* __restrict__ A, const unsigned short* __restrict__ Bt,
    unsigned short* __restrict__ qo, unsigned short* __restrict__ ko,
    _Float16* __restrict__ vo, float* __restrict__ fo,
    const float* __restrict__ bias, unsigned char* smem)
{
  unsigned short* As = (unsigned short*)smem;            // 16 KB
  unsigned short* Bs = (unsigned short*)(smem + 16384);  // 16 KB
  const int t = threadIdx.x;
  const int w = t >> 6, lane = t & 63;
  const int l15 = lane & 15, qd = lane >> 4;
  const int rsw = l15 & 7;
  const int m0 = by * 128, n0 = bx * 128;
  const int wm = (w >> 1) * 64, wn = (w & 1) * 64;

  int off[2];
#pragma unroll
  for (int j = 0; j < 2; j++) {
    int cl = j * 64 + lane;
    int r16 = cl >> 3, c = cl & 7;
    off[j] = r16 * DIM + ((c ^ (r16 & 7)) * 8);
  }
  const unsigned short* ga = A  + (size_t)(m0 + w * 16) * DIM;
  const unsigned short* gb = Bt + (size_t)(n0 + w * 16) * DIM;

  f32x4 acc[4][4] = {};

  for (int k0 = 0; k0 < DIM; k0 += 64) {
#pragma unroll
    for (int j = 0; j < 2; j++) {
      glds16(ga + k0 + off[j],            &As[w * 1024 + j * 512]);
      glds16(ga + 64 * DIM + k0 + off[j], &As[4096 + w * 1024 + j * 512]);
      glds16(gb + k0 + off[j],            &Bs[w * 1024 + j * 512]);
      glds16(gb + 64 * DIM + k0 + off[j], &Bs[4096 + w * 1024 + j * 512]);
    }
    __syncthreads();
#pragma unroll
    for (int ks = 0; ks < 2; ks++) {
      short8 af[4], bfr[4];
#pragma unroll
      for (int i = 0; i < 4; i++)
        af[i]  = *(const short8*)&As[(wm + i * 16 + l15) * 64 + (((ks * 4 + qd) ^ rsw)) * 8];
#pragma unroll
      for (int i = 0; i < 4; i++)
        bfr[i] = *(const short8*)&Bs[(wn + i * 16 + l15) * 64 + (((ks * 4 + qd) ^ rsw)) * 8];
#pragma unroll
      for (int mi = 0; mi < 4; mi++)
#pragma unroll
        for (int ni = 0; ni < 4; ni++)
          acc[mi][ni] = __builtin_amdgcn_mfma_f32_16x16x32_bf16(af[mi], bfr[ni], acc[mi][ni], 0, 0, 0);
    }
    __syncthreads();
  }

#pragma unroll
  for (int mi = 0; mi < 4; mi++)
#pragma unroll
    for (int ni = 0; ni < 4; ni++) {
      int rowb = m0 + wm + mi * 16 + qd * 4;
      int col  = n0 + wn + ni * 16 + l15;
      if (EPI == 0) {
        int b = rowb >> 11, n = rowb & 2047;
        int s = col / DIM;
        int rem = col - s * DIM;
        int hh = rem / DH;
        int c = rem - hh * DH;
        size_t bh = (size_t)(b * NH + hh);
        if (s == 2) {
          half4 pk;
#pragma unroll
          for (int r = 0; r < 4; r++) pk[r] = (_Float16)acc[mi][ni][r];
          *(half4*)&vo[(bh * DH + c) * NSEQ + n] = pk;
        } else if (s == 0) {
#pragma unroll
          for (int r = 0; r < 4; r++)
            qo[(bh * NSEQ + n + r) * DH + c] = f2bf(acc[mi][ni][r] * 0.1472444679f); // dh^-0.5*log2e
        } else {
#pragma unroll
          for (int r = 0; r < 4; r++)
            ko[(bh * NSEQ + n + r) * DH + c] = f2bf(acc[mi][ni][r]);
        }
      } else {
#pragma unroll
        for (int r = 0; r < 4; r++)
          fo[(size_t)(rowb + r) * DIM + col] = acc[mi][ni][r] + bias[col];
      }
    }
}

// flash attention v9 body (r2-exact): dbuf K/V, V-frag dedup, static-max softmax.
__device__ __forceinline__ void flash_block(
    int bid, const unsigned short* __restrict__ Qb, const unsigned short* __restrict__ Kb,
    const _Float16* __restrict__ Vtb, unsigned short* __restrict__ Z, unsigned char* smem)
{
  const int t = threadIdx.x, w = t >> 6, lane = t & 63;
  const int l15 = lane & 15, qd = lane >> 4;
  const int swz = (l15 >> 1) & 3;
  const int vswz = l15 & 7;

  const int h  = bid & 7;
  const int qt = (bid >> 3) & 15;
  const int b  = bid >> 7;

  const size_t bh = (size_t)(b * NH + h);
  const unsigned short* Qg = Qb + (bh * NSEQ + (size_t)qt * 128) * DH;
  const unsigned short* Kg = Kb + bh * NSEQ * DH;
  const _Float16*       Vg = Vtb + bh * (size_t)DH * NSEQ;

  int qoff[6];
#pragma unroll
  for (int i = 0; i < 6; i++) {
    int L = i * 256 + t;
    int r = L / 12, c = L - r * 12;
    qoff[i] = r * 96 + ((c ^ ((r >> 1) & 3)) * 8);
  }
  int koff[3];
#pragma unroll
  for (int i = 0; i < 3; i++) {
    int L = w * 192 + i * 64 + lane;
    int r = L / 12, c = L - r * 12;
    int fk = r >> 4, m = r & 15;
    int key = 32 * (fk & 1) + 4 * (fk >> 1) + 8 * (m >> 2) + (m & 3);
    koff[i] = key * 96 + ((c ^ ((r >> 1) & 3)) * 8);
  }
  int voff[3];
#pragma unroll
  for (int i = 0; i < 3; i++) {
    int L = i * 256 + t;
    int r = L >> 3, c = L & 7;
    voff[i] = r * NSEQ + ((c ^ (r & 7)) * 8);
  }

  short8 qa[2][3];
  f32x4 o[2][7] = {};
  const half8 onef = {(_Float16)1.f, (_Float16)1.f, (_Float16)1.f, (_Float16)1.f,
                      (_Float16)1.f, (_Float16)1.f, (_Float16)1.f, (_Float16)1.f};

  auto stageKV = [&](int kt, int bufoff) {
    unsigned short* Kd = (unsigned short*)(smem + bufoff);
    _Float16*       Vd = (_Float16*)(smem + bufoff + 12288);
    const unsigned short* Kt = Kg + (size_t)kt * 64 * DH;
#pragma unroll
    for (int i = 0; i < 3; i++)
      glds16(Kt + koff[i], &Kd[w * 1536 + i * 512]);
    const _Float16* Vt = Vg + kt * 64;
#pragma unroll
    for (int i = 0; i < 3; i++)
      glds16(Vt + voff[i], &Vd[(i * 256 + w * 64) * 8]);
  };

  auto compute = [&](int bufoff) {
    const unsigned short* Ks = (const unsigned short*)(smem + bufoff);
    const _Float16*       Vs = (const _Float16*)(smem + bufoff + 12288);

    f32x4 s[2][4] = {};
    __builtin_amdgcn_s_setprio(1);
#pragma unroll
    for (int ks = 0; ks < 3; ks++)
#pragma unroll
      for (int fk = 0; fk < 4; fk++) {
        short8 kf = *(const short8*)&Ks[(fk * 16 + l15) * 96 + ((ks * 4 + qd) ^ swz) * 8];
        s[0][fk] = __builtin_amdgcn_mfma_f32_16x16x32_bf16(kf, qa[0][ks], s[0][fk], 0, 0, 0);
        s[1][fk] = __builtin_amdgcn_mfma_f32_16x16x32_bf16(kf, qa[1][ks], s[1][fk], 0, 0, 0);
      }
    __builtin_amdgcn_s_setprio(0);

    half4 pf2[2][4];
#pragma unroll
    for (int fq = 0; fq < 2; fq++)
#pragma unroll
      for (int fk = 0; fk < 4; fk++) {
        union { fp16x2 h2[2]; half4 h4; } u;
        u.h2[0] = __builtin_amdgcn_cvt_pkrtz(fexp2(s[fq][fk][0] - 12.f), fexp2(s[fq][fk][1] - 12.f));
        u.h2[1] = __builtin_amdgcn_cvt_pkrtz(fexp2(s[fq][fk][2] - 12.f), fexp2(s[fq][fk][3] - 12.f));
        pf2[fq][fk] = u.h4;
      }

#pragma unroll
    for (int pp = 0; pp < 2; pp++) {
      union { half4 h4[2]; half8 h8; } bu0, bu1;
      bu0.h4[0] = pf2[0][pp]; bu0.h4[1] = pf2[0][pp + 2];
      bu1.h4[0] = pf2[1][pp]; bu1.h4[1] = pf2[1][pp + 2];
      __builtin_amdgcn_s_setprio(1);
#pragma unroll
      for (int fc = 0; fc < 6; fc++) {
        half8 vf = *(const half8*)&Vs[(fc * 16 + l15) * 64 + ((pp * 4 + qd) ^ vswz) * 8];
        o[0][fc] = __builtin_amdgcn_mfma_f32_16x16x32_f16(vf, bu0.h8, o[0][fc], 0, 0, 0);
        o[1][fc] = __builtin_amdgcn_mfma_f32_16x16x32_f16(vf, bu1.h8, o[1][fc], 0, 0, 0);
      }
      o[0][6] = __builtin_amdgcn_mfma_f32_16x16x32_f16(onef, bu0.h8, o[0][6], 0, 0, 0);
      o[1][6] = __builtin_amdgcn_mfma_f32_16x16x32_f16(onef, bu1.h8, o[1][6], 0, 0, 0);
      __builtin_amdgcn_s_setprio(0);
    }
  };

  // prologue: Q (buf0) + kt=0 (buf1)
#pragma unroll
  for (int i = 0; i < 6; i++)
    glds16(Qg + qoff[i], &((unsigned short*)smem)[i * 2048 + w * 512]);
  stageKV(0, 24576);
  __syncthreads();

  const unsigned short* Qs = (const unsigned short*)smem;
#pragma unroll
  for (int fq = 0; fq < 2; fq++)
#pragma unroll
    for (int ks = 0; ks < 3; ks++)
      qa[fq][ks] = *(const short8*)&Qs[(w * 32 + fq * 16 + l15) * 96 + ((ks * 4 + qd) ^ swz) * 8];
  __syncthreads();

  for (int kt = 0; kt < 32; kt += 2) {
    stageKV(kt + 1, 0);
    compute(24576);
    __syncthreads();
    if (kt < 30) stageKV(kt + 2, 24576);
    compute(0);
    __syncthreads();
  }

#pragma unroll
  for (int fq = 0; fq < 2; fq++) {
    float inv = 1.0f / o[fq][6][0];
    int q = qt * 128 + w * 32 + fq * 16 + l15;
    size_t zbase = ((size_t)b * NSEQ + h * 256 + (q >> 3)) * DIM + (q & 7) * DH;
#pragma unroll
    for (int fc = 0; fc < 6; fc++)
#pragma unroll
      for (int r = 0; r < 4; r += 2) {
        unsigned int pkd = (unsigned int)f2bf(o[fq][fc][r] * inv)
                         | ((unsigned int)f2bf(o[fq][fc][r + 1] * inv) << 16);
        *(unsigned int*)&Z[zbase + fc * 16 + qd * 4 + r] = pkd;
      }
  }
}

// =============================== kernels ===============================

// ---- mega-kernel: all 4 phases, manual grid barriers (512 blocks all-resident) ----
__global__ __launch_bounds__(256, 2) void mega_kernel(
    const float* __restrict__ x, const float* __restrict__ Wqkv,
    const float* __restrict__ Wo, const float* __restrict__ bo,
    unsigned short* __restrict__ xb, unsigned short* __restrict__ wqkvT,
    unsigned short* __restrict__ woT, unsigned short* __restrict__ Qw,
    unsigned short* __restrict__ Kw, _Float16* __restrict__ Vw,
    unsigned short* __restrict__ Zw, float* __restrict__ out,
    unsigned int* __restrict__ sync)
{
  __shared__ unsigned char smem[49152];
  const int bid = blockIdx.x;

  // P0: prep (grid-strided; same jobs as the 8448-block kernel)
  for (int j = bid; j < 6144; j += 512) prep_cvt_job(j, x, xb);
  for (int j = bid; j < 2304; j += 512) prep_wt_job(j, Wqkv, wqkvT, Wo, woT, smem);
  gridbar(sync, 512);

  // P1: gemm0 (1152 tile-jobs; tail round = 128 blocks, same as HW-scheduled tail)
  for (int j = bid; j < 1152; j += 512)
    gemm_tile<0>(j % 18, j / 18, xb, wqkvT, Qw, Kw, Vw, nullptr, nullptr, smem);
  gridbar(sync, 1024);

  // P2: flash (1:1)
  flash_block(bid, Qw, Kw, Vw, Zw, smem);
  gridbar(sync, 1536);

  // P3: gemm1 (384 jobs)
  if (bid < 384)
    gemm_tile<1>(bid % 6, bid / 6, Zw, woT, nullptr, nullptr, nullptr, out, bo, smem);
}

// ---- fallback wrappers (r2-exact 4-launch path, used if ws_size lacks sync slot) ----
__global__ __launch_bounds__(256) void prep_kernel(
    const float* __restrict__ x, unsigned short* __restrict__ xb,
    const float* __restrict__ Wqkv, unsigned short* __restrict__ wqkvT,
    const float* __restrict__ Wo, unsigned short* __restrict__ woT)
{
  __shared__ unsigned char smem[4224];
  int blk = blockIdx.x;
  if (blk < 6144) { prep_cvt_job(blk, x, xb); return; }
  prep_wt_job(blk - 6144, Wqkv, wqkvT, Wo, woT, smem);
}

template <int EPI>
__global__ __launch_bounds__(256) void gemm_bt(
    const unsigned short* __restrict__ A, const unsigned short* __restrict__ Bt,
    unsigned short* __restrict__ qo, unsigned short* __restrict__ ko,
    _Float16* __restrict__ vo, float* __restrict__ fo,
    const float* __restrict__ bias)
{
  __shared__ unsigned char smem[32768];
  gemm_tile<EPI>(blockIdx.x, blockIdx.y, A, Bt, qo, ko, vo, fo, bias, smem);
}

__global__ __launch_bounds__(256, 2) void flash_kernel(
    const unsigned short* __restrict__ Qb, const unsigned short* __restrict__ Kb,
    const _Float16* __restrict__ Vtb, unsigned short* __restrict__ Z)
{
  __shared__ unsigned char smem[49152];
  flash_block(blockIdx.x, Qb, Kb, Vtb, Z, smem);
}

extern "C" void kernel_launch(void* const* d_in, const int* in_sizes, int n_in,
                              void* d_out, int out_size, void* d_ws, size_t ws_size,
                              hipStream_t stream)
{
  (void)in_sizes; (void)n_in; (void)out_size;
  const float* x    = (const float*)d_in[0];
  const float* Wqkv = (const float*)d_in[1];
  const float* Wo   = (const float*)d_in[2];
  const float* bo   = (const float*)d_in[3];
  float* out = (float*)d_out;

  unsigned short* ws    = (unsigned short*)d_ws;
  unsigned short* xb    = ws;                              // 8192*768
  unsigned short* wqkvT = xb    + (size_t)8192 * 768;      // 2304*768
  unsigned short* woT   = wqkvT + (size_t)2304 * 768;      // 768*768
  unsigned short* Qw    = woT   + (size_t)768 * 768;       // 4*8*2048*96 bf16
  unsigned short* Kw    = Qw    + (size_t)6291456;         // bf16
  _Float16*       Vw    = (_Float16*)(Kw + (size_t)6291456); // fp16 V^T
  unsigned short* Zw    = (unsigned short*)(Vw + (size_t)6291456); // 8192*768 bf16

  const size_t base = 67633152;                            // bytes used through Zw
  if (ws_size >= base + 64) {
    unsigned int* sync = (unsigned int*)((char*)d_ws + base);
    hipMemsetAsync(sync, 0, 64, stream);                   // counter reset per replay
    mega_kernel<<<512, 256, 0, stream>>>(x, Wqkv, Wo, bo, xb, wqkvT, woT,
                                         Qw, Kw, Vw, Zw, out, sync);
  } else {
    prep_kernel<<<8448, 256, 0, stream>>>(x, xb, Wqkv, wqkvT, Wo, woT);
    gemm_bt<0><<<dim3(18, 64), 256, 0, stream>>>(xb, wqkvT, Qw, Kw, Vw, nullptr, nullptr);
    flash_kernel<<<512, 256, 0, stream>>>(Qw, Kw, Vw, Zw);
    gemm_bt<1><<<dim3(6, 64), 256, 0, stream>>>(Zw, woT, nullptr, nullptr, nullptr, out, bo);
  }
}

// Round 10
// 207.458 us; speedup vs baseline: 3.2856x; 3.2856x over previous
//
#include <hip/hip_runtime.h>

typedef __attribute__((ext_vector_type(8))) short short8;
typedef __attribute__((ext_vector_type(4))) float f32x4;
typedef __attribute__((ext_vector_type(4))) _Float16 half4;
typedef __attribute__((ext_vector_type(8))) _Float16 half8;
typedef __attribute__((ext_vector_type(2))) __fp16 fp16x2;

#define B_SZ 4
#define NSEQ 2048
#define DIM  768
#define NH   8
#define DH   96

__device__ __forceinline__ unsigned short f2bf(float f) {
  unsigned int u = __float_as_uint(f);
  u += 0x7fffu + ((u >> 16) & 1u);   // RNE
  return (unsigned short)(u >> 16);
}

__device__ __forceinline__ float fexp2(float x) {
#if __has_builtin(__builtin_amdgcn_exp2f)
  return __builtin_amdgcn_exp2f(x);
#else
  return exp2f(x);
#endif
}

__device__ __forceinline__ void glds16(const void* g, void* l) {
  __builtin_amdgcn_global_load_lds((const __attribute__((address_space(1))) void*)g,
                                   (__attribute__((address_space(3))) void*)l, 16, 0, 0);
}

// ---------------- fused prep: x->bf16 convert + both weight transposes ----------------
// blocks [0,6144): cvt x (one float4/thread); [6144,7872): W_qkv^T; [7872,8448): W_o^T
__global__ __launch_bounds__(256) void prep_kernel(
    const float* __restrict__ x, unsigned short* __restrict__ xb,
    const float* __restrict__ Wqkv, unsigned short* __restrict__ wqkvT,
    const float* __restrict__ Wo, unsigned short* __restrict__ woT)
{
  int blk = blockIdx.x;
  if (blk < 6144) {
    int i = blk * 256 + threadIdx.x;
    float4 v = ((const float4*)x)[i];
    ushort4 o;
    o.x = f2bf(v.x); o.y = f2bf(v.y); o.z = f2bf(v.z); o.w = f2bf(v.w);
    ((ushort4*)xb)[i] = o;
    return;
  }
  __shared__ float tile[32][33];
  const float* W; unsigned short* WT; int ncols, bx, by;
  if (blk < 7872) { int r = blk - 6144; W = Wqkv; WT = wqkvT; ncols = 2304; bx = r % 72; by = r / 72; }
  else            { int r = blk - 7872; W = Wo;   WT = woT;   ncols = 768;  bx = r % 24; by = r / 24; }
  int tx = threadIdx.x & 31, ty = threadIdx.x >> 5;      // 32 x 8
  int c0 = bx * 32, r0 = by * 32;
#pragma unroll
  for (int i = 0; i < 4; i++)
    tile[ty + i * 8][tx] = W[(size_t)(r0 + ty + i * 8) * ncols + c0 + tx];
  __syncthreads();
#pragma unroll
  for (int i = 0; i < 4; i++)
    WT[(size_t)(c0 + ty + i * 8) * 768 + r0 + tx] = f2bf(tile[tx][ty + i * 8]);
}

// ---------------- bf16 GEMM, A[M][768] @ Bt[N][768]^T, 128x128 tile, BK=64 ---------------
// EPI 0: scatter epilogue -> Q (scaled by dh^-0.5*log2e), K (bf16), V^T (fp16, 8B packed)
// EPI 1: +bias, fp32 out
template <int EPI>
__global__ __launch_bounds__(256) void gemm_bt(
    const unsigned short* __restrict__ A, const unsigned short* __restrict__ Bt,
    unsigned short* __restrict__ qo, unsigned short* __restrict__ ko,
    _Float16* __restrict__ vo, float* __restrict__ fo,
    const float* __restrict__ bias)
{
  __shared__ unsigned short As[128 * 64];   // 16 KB
  __shared__ unsigned short Bs[128 * 64];   // 16 KB
  const int t = threadIdx.x;
  const int w = t >> 6, lane = t & 63;
  const int l15 = lane & 15, qd = lane >> 4;
  const int rsw = l15 & 7;                 // read-side chunk XOR (row&7 == l15&7)
  const int m0 = blockIdx.y * 128, n0 = blockIdx.x * 128;
  const int wm = (w >> 1) * 64, wn = (w & 1) * 64;

  int off[2];
#pragma unroll
  for (int j = 0; j < 2; j++) {
    int cl = j * 64 + lane;
    int r16 = cl >> 3, c = cl & 7;
    off[j] = r16 * DIM + ((c ^ (r16 & 7)) * 8);
  }
  const unsigned short* ga = A  + (size_t)(m0 + w * 16) * DIM;
  const unsigned short* gb = Bt + (size_t)(n0 + w * 16) * DIM;

  f32x4 acc[4][4] = {};

  for (int k0 = 0; k0 < DIM; k0 += 64) {
#pragma unroll
    for (int j = 0; j < 2; j++) {
      glds16(ga + k0 + off[j],            &As[w * 1024 + j * 512]);
      glds16(ga + 64 * DIM + k0 + off[j], &As[4096 + w * 1024 + j * 512]);
      glds16(gb + k0 + off[j],            &Bs[w * 1024 + j * 512]);
      glds16(gb + 64 * DIM + k0 + off[j], &Bs[4096 + w * 1024 + j * 512]);
    }
    __syncthreads();
#pragma unroll
    for (int ks = 0; ks < 2; ks++) {
      short8 af[4], bfr[4];
#pragma unroll
      for (int i = 0; i < 4; i++)
        af[i]  = *(const short8*)&As[(wm + i * 16 + l15) * 64 + (((ks * 4 + qd) ^ rsw)) * 8];
#pragma unroll
      for (int i = 0; i < 4; i++)
        bfr[i] = *(const short8*)&Bs[(wn + i * 16 + l15) * 64 + (((ks * 4 + qd) ^ rsw)) * 8];
#pragma unroll
      for (int mi = 0; mi < 4; mi++)
#pragma unroll
        for (int ni = 0; ni < 4; ni++)
          acc[mi][ni] = __builtin_amdgcn_mfma_f32_16x16x32_bf16(af[mi], bfr[ni], acc[mi][ni], 0, 0, 0);
    }
    __syncthreads();
  }

#pragma unroll
  for (int mi = 0; mi < 4; mi++)
#pragma unroll
    for (int ni = 0; ni < 4; ni++) {
      int rowb = m0 + wm + mi * 16 + qd * 4;   // 4 consecutive rows per lane
      int col  = n0 + wn + ni * 16 + l15;
      if (EPI == 0) {
        int b = rowb >> 11, n = rowb & 2047;
        int s = col / DIM;                     // uniform per block (128 | 768)
        int rem = col - s * DIM;
        int hh = rem / DH;
        int c = rem - hh * DH;
        size_t bh = (size_t)(b * NH + hh);
        if (s == 2) {                          // V^T: 4 consecutive n at fixed c -> one 8B store
          half4 pk;
#pragma unroll
          for (int r = 0; r < 4; r++) pk[r] = (_Float16)acc[mi][ni][r];
          *(half4*)&vo[(bh * DH + c) * NSEQ + n] = pk;
        } else if (s == 0) {
#pragma unroll
          for (int r = 0; r < 4; r++)
            qo[(bh * NSEQ + n + r) * DH + c] = f2bf(acc[mi][ni][r] * 0.1472444679f); // dh^-0.5*log2e
        } else {
#pragma unroll
          for (int r = 0; r < 4; r++)
            ko[(bh * NSEQ + n + r) * DH + c] = f2bf(acc[mi][ni][r]);
        }
      } else {
#pragma unroll
        for (int r = 0; r < 4; r++)
          fo[(size_t)(rowb + r) * DIM + col] = acc[mi][ni][r] + bias[col];
      }
    }
}

// ---------------- flash attention v9: dbuf K/V + V-fragment dedup (207.9 us config) ------
// Per kt-pair: stage other buffer, compute current {QK^T -> static-max softmax -> PV},
// one barrier per kt. Each V fragment read ONCE from LDS and feeds both fq MFMAs
// (LDS reads 24/kt/wave). Static-max softmax p = exp2(s-12), exact after final 1/l.
// XCD-grouped 1-D grid: bid%8 == h keeps a (b,h)'s K/V panel on one XCD L2
// (FETCH 104 -> 18.5 MB, measured r1).
__global__ __launch_bounds__(256, 2) void flash_kernel(
    const unsigned short* __restrict__ Qb, const unsigned short* __restrict__ Kb,
    const _Float16* __restrict__ Vtb, unsigned short* __restrict__ Z)
{
  __shared__ unsigned char smem[49152];      // buf0 @0, buf1 @24576; each: K 12288 | V 12288

  const int t = threadIdx.x, w = t >> 6, lane = t & 63;
  const int l15 = lane & 15, qd = lane >> 4;
  const int swz = (l15 >> 1) & 3;
  const int vswz = l15 & 7;

  const int bid = blockIdx.x;
  const int h  = bid & 7;
  const int qt = (bid >> 3) & 15;
  const int b  = bid >> 7;

  const size_t bh = (size_t)(b * NH + h);
  const unsigned short* Qg = Qb + (bh * NSEQ + (size_t)qt * 128) * DH;
  const unsigned short* Kg = Kb + bh * NSEQ * DH;
  const _Float16*       Vg = Vtb + bh * (size_t)DH * NSEQ;

  int qoff[6];
#pragma unroll
  for (int i = 0; i < 6; i++) {
    int L = i * 256 + t;
    int r = L / 12, c = L - r * 12;
    qoff[i] = r * 96 + ((c ^ ((r >> 1) & 3)) * 8);
  }
  int koff[3];
#pragma unroll
  for (int i = 0; i < 3; i++) {
    int L = w * 192 + i * 64 + lane;
    int r = L / 12, c = L - r * 12;
    int fk = r >> 4, m = r & 15;
    int key = 32 * (fk & 1) + 4 * (fk >> 1) + 8 * (m >> 2) + (m & 3);
    koff[i] = key * 96 + ((c ^ ((r >> 1) & 3)) * 8);
  }
  int voff[3];
#pragma unroll
  for (int i = 0; i < 3; i++) {
    int L = i * 256 + t;
    int r = L >> 3, c = L & 7;
    voff[i] = r * NSEQ + ((c ^ (r & 7)) * 8);
  }

  short8 qa[2][3];
  f32x4 o[2][7] = {};                          // [fq][0..5]=O^T frags, [fq][6]=row-sum
  const half8 onef = {(_Float16)1.f, (_Float16)1.f, (_Float16)1.f, (_Float16)1.f,
                      (_Float16)1.f, (_Float16)1.f, (_Float16)1.f, (_Float16)1.f};

  auto stageKV = [&](int kt, int bufoff) {
    unsigned short* Kd = (unsigned short*)(smem + bufoff);
    _Float16*       Vd = (_Float16*)(smem + bufoff + 12288);
    const unsigned short* Kt = Kg + (size_t)kt * 64 * DH;
#pragma unroll
    for (int i = 0; i < 3; i++)
      glds16(Kt + koff[i], &Kd[w * 1536 + i * 512]);
    const _Float16* Vt = Vg + kt * 64;
#pragma unroll
    for (int i = 0; i < 3; i++)
      glds16(Vt + voff[i], &Vd[(i * 256 + w * 64) * 8]);
  };

  auto compute = [&](int bufoff) {
    const unsigned short* Ks = (const unsigned short*)(smem + bufoff);
    const _Float16*       Vs = (const _Float16*)(smem + bufoff + 12288);

    // ---- S^T = K·Q^T for both q-groups: s[fq][fk][r] = key 32(fk&1)+4(fk>>1)+8qd+r ----
    f32x4 s[2][4] = {};
    __builtin_amdgcn_s_setprio(1);
#pragma unroll
    for (int ks = 0; ks < 3; ks++)
#pragma unroll
      for (int fk = 0; fk < 4; fk++) {
        short8 kf = *(const short8*)&Ks[(fk * 16 + l15) * 96 + ((ks * 4 + qd) ^ swz) * 8];
        s[0][fk] = __builtin_amdgcn_mfma_f32_16x16x32_bf16(kf, qa[0][ks], s[0][fk], 0, 0, 0);
        s[1][fk] = __builtin_amdgcn_mfma_f32_16x16x32_bf16(kf, qa[1][ks], s[1][fk], 0, 0, 0);
      }
    __builtin_amdgcn_s_setprio(0);

    // ---- static-max softmax for BOTH q-groups: p = exp2(s - 12) ----
    half4 pf2[2][4];
#pragma unroll
    for (int fq = 0; fq < 2; fq++)
#pragma unroll
      for (int fk = 0; fk < 4; fk++) {
        union { fp16x2 h2[2]; half4 h4; } u;
        u.h2[0] = __builtin_amdgcn_cvt_pkrtz(fexp2(s[fq][fk][0] - 12.f), fexp2(s[fq][fk][1] - 12.f));
        u.h2[1] = __builtin_amdgcn_cvt_pkrtz(fexp2(s[fq][fk][2] - 12.f), fexp2(s[fq][fk][3] - 12.f));
        pf2[fq][fk] = u.h4;
      }

    // ---- O^T += V^T · P^T, each V fragment loaded ONCE, feeds both fq ----
#pragma unroll
    for (int pp = 0; pp < 2; pp++) {
      union { half4 h4[2]; half8 h8; } bu0, bu1;
      bu0.h4[0] = pf2[0][pp]; bu0.h4[1] = pf2[0][pp + 2];
      bu1.h4[0] = pf2[1][pp]; bu1.h4[1] = pf2[1][pp + 2];
      __builtin_amdgcn_s_setprio(1);
#pragma unroll
      for (int fc = 0; fc < 6; fc++) {
        half8 vf = *(const half8*)&Vs[(fc * 16 + l15) * 64 + ((pp * 4 + qd) ^ vswz) * 8];
        o[0][fc] = __builtin_amdgcn_mfma_f32_16x16x32_f16(vf, bu0.h8, o[0][fc], 0, 0, 0);
        o[1][fc] = __builtin_amdgcn_mfma_f32_16x16x32_f16(vf, bu1.h8, o[1][fc], 0, 0, 0);
      }
      o[0][6] = __builtin_amdgcn_mfma_f32_16x16x32_f16(onef, bu0.h8, o[0][6], 0, 0, 0);
      o[1][6] = __builtin_amdgcn_mfma_f32_16x16x32_f16(onef, bu1.h8, o[1][6], 0, 0, 0);
      __builtin_amdgcn_s_setprio(0);
    }
  };

  // ---- prologue: stage Q (buf0) + kt=0 K/V (buf1); pull Q register fragments ----
#pragma unroll
  for (int i = 0; i < 6; i++)
    glds16(Qg + qoff[i], &((unsigned short*)smem)[i * 2048 + w * 512]);
  stageKV(0, 24576);
  __syncthreads();                             // drains vmcnt(0): Q and kt0 both landed

  const unsigned short* Qs = (const unsigned short*)smem;
#pragma unroll
  for (int fq = 0; fq < 2; fq++)
#pragma unroll
    for (int ks = 0; ks < 3; ks++)
      qa[fq][ks] = *(const short8*)&Qs[(w * 32 + fq * 16 + l15) * 96 + ((ks * 4 + qd) ^ swz) * 8];
  __syncthreads();                             // all waves done reading Q -> buf0 reusable

  // ---- main loop: prefetch(kt+1) into other buffer, compute kt, one barrier/kt ----
  for (int kt = 0; kt < 32; kt += 2) {
    stageKV(kt + 1, 0);                        // kt+1 <= 31 always
    compute(24576);
    __syncthreads();
    if (kt < 30) stageKV(kt + 2, 24576);
    compute(0);
    __syncthreads();
  }

  // ---- epilogue: O/l, write Z with head-mixing reshape folded in ----
#pragma unroll
  for (int fq = 0; fq < 2; fq++) {
    float inv = 1.0f / o[fq][6][0];            // all rows of ones-frag equal the row-sum
    int q = qt * 128 + w * 32 + fq * 16 + l15;
    size_t zbase = ((size_t)b * NSEQ + h * 256 + (q >> 3)) * DIM + (q & 7) * DH;
#pragma unroll
    for (int fc = 0; fc < 6; fc++)
#pragma unroll
      for (int r = 0; r < 4; r += 2) {
        unsigned int pkd = (unsigned int)f2bf(o[fq][fc][r] * inv)
                         | ((unsigned int)f2bf(o[fq][fc][r + 1] * inv) << 16);
        *(unsigned int*)&Z[zbase + fc * 16 + qd * 4 + r] = pkd;
      }
  }
}

extern "C" void kernel_launch(void* const* d_in, const int* in_sizes, int n_in,
                              void* d_out, int out_size, void* d_ws, size_t ws_size,
                              hipStream_t stream)
{
  (void)in_sizes; (void)n_in; (void)out_size; (void)ws_size;
  const float* x    = (const float*)d_in[0];
  const float* Wqkv = (const float*)d_in[1];
  const float* Wo   = (const float*)d_in[2];
  const float* bo   = (const float*)d_in[3];
  float* out = (float*)d_out;

  unsigned short* ws    = (unsigned short*)d_ws;
  unsigned short* xb    = ws;                              // 8192*768
  unsigned short* wqkvT = xb    + (size_t)8192 * 768;      // 2304*768
  unsigned short* woT   = wqkvT + (size_t)2304 * 768;      // 768*768
  unsigned short* Qw    = woT   + (size_t)768 * 768;       // 4*8*2048*96 bf16
  unsigned short* Kw    = Qw    + (size_t)6291456;         // bf16
  _Float16*       Vw    = (_Float16*)(Kw + (size_t)6291456); // fp16 V^T
  unsigned short* Zw    = (unsigned short*)(Vw + (size_t)6291456); // 8192*768 bf16

  prep_kernel<<<8448, 256, 0, stream>>>(x, xb, Wqkv, wqkvT, Wo, woT);
  gemm_bt<0><<<dim3(18, 64), 256, 0, stream>>>(xb, wqkvT, Qw, Kw, Vw, nullptr, nullptr);
  flash_kernel<<<512, 256, 0, stream>>>(Qw, Kw, Vw, Zw);
  gemm_bt<1><<<dim3(6, 64), 256, 0, stream>>>(Zw, woT, nullptr, nullptr, nullptr, out, bo);
}